// Round 16
// baseline (799.540 us; speedup 1.0000x reference)
//
#include <hip/hip_runtime.h>

#define S_TOK 32768
#define DIN   2048
#define NH    8
#define NG    4
#define DH    128
#define NSINK 16
#define BK    64

typedef float        f32x4  __attribute__((ext_vector_type(4)));
typedef float        f32x16 __attribute__((ext_vector_type(16)));
typedef short        s16x8  __attribute__((ext_vector_type(8)));
typedef unsigned int u32x4  __attribute__((ext_vector_type(4)));

#define UR _Pragma("unroll")

__device__ __forceinline__ unsigned short f2bf(float f) {
    unsigned int u = __builtin_bit_cast(unsigned int, f);
    u = (u + 0x7fffu + ((u >> 16) & 1u)) >> 16;
    return (unsigned short)u;
}
__device__ __forceinline__ float bf2f(unsigned short h) {
    unsigned int u = ((unsigned int)h) << 16;
    return __builtin_bit_cast(float, u);
}
__device__ __forceinline__ unsigned int pack2(float lo, float hi) {
    return (unsigned int)f2bf(lo) | ((unsigned int)f2bf(hi) << 16);
}

// ---------------- fused fp32 -> bf16 pre-conversion (3 segments, 1 launch)
__global__ __launch_bounds__(256) void cvt_all_kernel(const float* __restrict__ hid,
                                                      const float* __restrict__ wq,
                                                      const float* __restrict__ wk,
                                                      unsigned short* __restrict__ ohid,
                                                      unsigned short* __restrict__ owq,
                                                      unsigned short* __restrict__ owk)
{
    const float* in;
    unsigned short* out;
    int n8, i, stride;
    if (blockIdx.x < 2048) {
        in = hid; out = ohid; n8 = (S_TOK * DIN) / 8;
        i = blockIdx.x * 256 + threadIdx.x; stride = 2048 * 256;
    } else if (blockIdx.x < 2560) {
        in = wq; out = owq; n8 = (NH * NG * DH * DIN) / 8;
        i = (blockIdx.x - 2048) * 256 + threadIdx.x; stride = 512 * 256;
    } else {
        in = wk; out = owk; n8 = (NH * DH * DIN) / 8;
        i = (blockIdx.x - 2560) * 256 + threadIdx.x; stride = 256 * 256;
    }
    for (; i < n8; i += stride) {
        const float* p = in + (size_t)i * 8;
        float4 a = *(const float4*)p;
        float4 b = *(const float4*)(p + 4);
        u32x4 v;
        v.x = pack2(a.x, a.y); v.y = pack2(a.z, a.w);
        v.z = pack2(b.x, b.y); v.w = pack2(b.z, b.w);
        *(u32x4*)(out + (size_t)i * 8) = v;
    }
}

// ---------------- Kernel A (R13-proven, frozen): k-proj 256x256 tile
__global__ __launch_bounds__(512, 2) void kproj256_bf16(const unsigned short* __restrict__ hid,
                                                        const unsigned short* __restrict__ Wk,
                                                        const float* __restrict__ knw,
                                                        unsigned short* __restrict__ kn_ws)
{
    __shared__ alignas(16) unsigned short smem[65536];
    __shared__ float wsm[128];
    unsigned short (*qsc)[132] = (unsigned short(*)[132])smem;

    const int tid = threadIdx.x, lane = tid & 63, wv = tid >> 6;
    const int wm = wv >> 2, wn = wv & 3;
    const int nt = blockIdx.x;
    const int m0 = blockIdx.y * 256;
    const int n0 = nt * 256;

    if (tid < 128) wsm[tid] = knw[tid];

    const int srow = tid >> 3;
    const int so0 = srow * DIN + (((tid & 7) ^ (srow & 7)) * 8);

    const int l15 = lane & 15;
    const int slotA = ((lane >> 4) ^ (lane & 7)) * 8;
    const int aOff0 = (wm * 128 + l15) * 64 + slotA;
    const int aOff1 = aOff0 ^ 32;
    const int bOff0 = (wn * 64 + l15) * 64 + slotA;
    const int bOff1 = bOff0 ^ 32;

    const unsigned short* aStage = hid + (size_t)m0 * DIN;
    const unsigned short* bStage = Wk + (size_t)n0 * DIN;

    f32x4 acc[8][4];
    UR for (int m = 0; m < 8; ++m)
        UR for (int n = 0; n < 4; ++n)
            acc[m][n] = f32x4{0.f, 0.f, 0.f, 0.f};

    s16x8 aF[4][2], bF[4][2];

#define GL(LDSB, SRC)                                                                              \
    __builtin_amdgcn_global_load_lds(                                                              \
        (const __attribute__((address_space(1))) unsigned int*)((SRC) + so0),                      \
        (__attribute__((address_space(3))) unsigned int*)(smem + (LDSB) + tid * 8), 16, 0, 0);     \
    __builtin_amdgcn_global_load_lds(                                                              \
        (const __attribute__((address_space(1))) unsigned int*)((SRC) + so0 + 64 * DIN),           \
        (__attribute__((address_space(3))) unsigned int*)(smem + (LDSB) + 4096 + tid * 8), 16, 0, 0);

#define GLALL(BUFW)                                                                                \
    { GL((BUFW) + 0,     aStage)             GL((BUFW) + 8192,  aStage + 128 * DIN)                \
      GL((BUFW) + 16384, bStage)             GL((BUFW) + 24576, bStage + 128 * DIN) }

#define LDA(BUF, QH)                                                                               \
    { UR for (int i_ = 0; i_ < 4; ++i_) {                                                          \
        aF[i_][0] = *(const s16x8*)&smem[(BUF) + aOff0 + ((QH) * 4 + i_) * 1024];                  \
        aF[i_][1] = *(const s16x8*)&smem[(BUF) + aOff1 + ((QH) * 4 + i_) * 1024]; } }

#define LDB(BUF, NH2)                                                                              \
    { UR for (int j_ = 0; j_ < 2; ++j_) {                                                          \
        bF[(NH2) * 2 + j_][0] = *(const s16x8*)&smem[(BUF) + 16384 + bOff0 + ((NH2) * 2 + j_) * 1024]; \
        bF[(NH2) * 2 + j_][1] = *(const s16x8*)&smem[(BUF) + 16384 + bOff1 + ((NH2) * 2 + j_) * 1024]; } }

#define MFMAQ(MF0, NF0)                                                                            \
    { __builtin_amdgcn_s_setprio(1);                                                               \
      UR for (int i_ = 0; i_ < 4; ++i_)                                                            \
        UR for (int j_ = 0; j_ < 2; ++j_)                                                          \
          UR for (int k_ = 0; k_ < 2; ++k_)                                                        \
            acc[(MF0) + i_][(NF0) + j_] = __builtin_amdgcn_mfma_f32_16x16x32_bf16(                 \
                aF[i_][k_], bF[(NF0) + j_][k_], acc[(MF0) + i_][(NF0) + j_], 0, 0, 0);             \
      __builtin_amdgcn_s_setprio(0); }

#define TILE(BUFR, BUFW, DOSTAGE)                                                                  \
    {                                                                                              \
        LDA(BUFR, 0); LDB(BUFR, 0);                                                                \
        if (DOSTAGE) { GLALL(BUFW); aStage += BK; bStage += BK; }                                  \
        MFMAQ(0, 0);                                                                               \
        LDB(BUFR, 1);                                                                              \
        MFMAQ(0, 2);                                                                               \
        LDA(BUFR, 1);                                                                              \
        MFMAQ(4, 2);                                                                               \
        MFMAQ(4, 0);                                                                               \
        asm volatile("s_waitcnt vmcnt(0)" ::: "memory");                                           \
        asm volatile("s_barrier" ::: "memory");                                                    \
    }

    GLALL(0)
    aStage += BK; bStage += BK;
    asm volatile("s_waitcnt vmcnt(0)" ::: "memory");
    asm volatile("s_barrier" ::: "memory");

    for (int i = 0; i < 15; ++i) {
        TILE(0, 32768, 1);
        TILE(32768, 0, 1);
    }
    TILE(0, 32768, 1);
    TILE(32768, 0, 0);

#undef GL
#undef GLALL
#undef LDA
#undef LDB
#undef MFMAQ
#undef TILE

    for (int c = 0; c < 2; ++c) {
        if (((wv >> 1) & 1) == c) {
            UR for (int mf = 0; mf < 8; ++mf)
                UR for (int nf = 0; nf < 4; ++nf)
                    UR for (int r = 0; r < 4; ++r)
                        qsc[wm * 128 + mf * 16 + (lane >> 4) * 4 + r][(wv & 1) * 64 + nf * 16 + l15] =
                            f2bf(acc[mf][nf][r]);
        }
        __syncthreads();

        {
            const int r2 = tid >> 1, ch = (tid & 1) * 64;
            const unsigned short* row = &qsc[r2][ch];
            float s2 = 0.f;
            UR for (int dw = 0; dw < 32; ++dw) {
                unsigned int v = *(const unsigned int*)&row[dw * 2];
                float f0 = bf2f((unsigned short)(v & 0xffff));
                float f1 = bf2f((unsigned short)(v >> 16));
                s2 += f0 * f0 + f1 * f1;
            }
            s2 += __shfl_xor(s2, 1);
            const float rq = rsqrtf(s2 * (1.0f / 128.0f) + 1e-6f);

            const int hc = nt * 2 + c;
            unsigned short* dst = kn_ws + (size_t)(m0 + r2) * (NH * DH) + hc * DH + ch;
            UR for (int i = 0; i < 8; ++i) {
                u32x4 v;
                float f0, f1;
                f0 = bf2f(row[i * 8 + 0]) * rq * wsm[ch + i * 8 + 0];
                f1 = bf2f(row[i * 8 + 1]) * rq * wsm[ch + i * 8 + 1];
                v.x = pack2(f0, f1);
                f0 = bf2f(row[i * 8 + 2]) * rq * wsm[ch + i * 8 + 2];
                f1 = bf2f(row[i * 8 + 3]) * rq * wsm[ch + i * 8 + 3];
                v.y = pack2(f0, f1);
                f0 = bf2f(row[i * 8 + 4]) * rq * wsm[ch + i * 8 + 4];
                f1 = bf2f(row[i * 8 + 5]) * rq * wsm[ch + i * 8 + 5];
                v.z = pack2(f0, f1);
                f0 = bf2f(row[i * 8 + 6]) * rq * wsm[ch + i * 8 + 6];
                f1 = bf2f(row[i * 8 + 7]) * rq * wsm[ch + i * 8 + 7];
                v.w = pack2(f0, f1);
                *(u32x4*)(dst + i * 8) = v;
            }
        }
        __syncthreads();
    }
}

// ---------------- Kernel B (R16): 256x256 tile, R8 coarse schedule, 32x32x16 MFMA.
// Wave tile 128x64 = 4x2 grid of 32x32 output tiles; 32 MFMA/K-tile/wave (was 64 of
// 16x16x32). Same FLOPs, but 32x32 shape runs at 2495 TF ubench vs 2075 (m119/m06):
// ~17% fewer MFMA-pipe cycles. LDS layout, staging, swizzle, schedule all unchanged.
// A/B frag: row = lane&31, k = (lane>>5)*8 + j  (granule g = ks*2 + (lane>>5)).
// C/D layout (m74/m101-verified): col = lane&31, row = (reg&3) + 8*(reg>>2) + 4*(lane>>5).
__global__ __launch_bounds__(512, 2) void qscore_bf16(const unsigned short* __restrict__ hid,
                                                      const unsigned short* __restrict__ Wq,
                                                      const float* __restrict__ bq,
                                                      const float* __restrict__ qnw,
                                                      const float* __restrict__ bb,
                                                      const float* __restrict__ kbase,
                                                      const unsigned short* __restrict__ kn_ws,
                                                      float* __restrict__ out)
{
    __shared__ alignas(16) unsigned short smem[65536];
    __shared__ alignas(16) unsigned short kbn[NSINK][136];
    __shared__ float rms_l[256];
    __shared__ float l_l[256];
    __shared__ float wsm[128];
    unsigned short (*qsc)[132] = (unsigned short(*)[132])smem;

    const int tid = threadIdx.x, lane = tid & 63, wv = tid >> 6;
    const int wm = wv >> 2, wn = wv & 3;
    const int nt = blockIdx.x;
    const int m0 = blockIdx.y * 256;
    const int n0 = nt * 256;
    const int h  = nt >> 1;

    if (tid < 128) wsm[tid] = qnw[tid];
    if (tid < 256) {
        const int ts = tid >> 4, d0 = (tid & 15) * 8;
        const float* src = kbase + ((size_t)h * NSINK + ts) * DH + d0;
        float4 x = *(const float4*)src;
        float4 y = *(const float4*)(src + 4);
        const float* w = qnw + d0;
        u32x4 v;
        v.x = pack2(x.x * w[0], x.y * w[1]);
        v.y = pack2(x.z * w[2], x.w * w[3]);
        v.z = pack2(y.x * w[4], y.y * w[5]);
        v.w = pack2(y.z * w[6], y.w * w[7]);
        *(u32x4*)&kbn[ts][d0] = v;
    }

    const int srow = tid >> 3;
    const int so0 = srow * DIN + (((tid & 7) ^ (srow & 7)) * 8);

    const int l15 = lane & 15;
    const int l31 = lane & 31;
    const int lk  = lane >> 5;                  // 0/1: which 8-elem k-slice of the slab
    // frag bases: row&7 == lane&7 for all tiles (tile rows are 32-aligned)
    const int aBase = (wm * 128 + l31) * 64;            // + mt*2048 + sA[ks]
    const int bBase = 16384 + (wn * 64 + l31) * 64;     // + nt*2048 + sA[ks]
    int sA[4];
    UR for (int ks = 0; ks < 4; ++ks)
        sA[ks] = ((ks * 2 + lk) ^ (lane & 7)) * 8;

    const unsigned short* aStage = hid + (size_t)m0 * DIN;
    const unsigned short* bStage = Wq + (size_t)n0 * DIN;

    f32x16 acc[4][2];
    UR for (int m = 0; m < 4; ++m)
        UR for (int n = 0; n < 2; ++n)
            UR for (int e = 0; e < 16; ++e)
                acc[m][n][e] = 0.f;

    s16x8 aF[4][2], bF[2][2];

#define GL(LDSB, SRC)                                                                              \
    __builtin_amdgcn_global_load_lds(                                                              \
        (const __attribute__((address_space(1))) unsigned int*)((SRC) + so0),                      \
        (__attribute__((address_space(3))) unsigned int*)(smem + (LDSB) + tid * 8), 16, 0, 0);     \
    __builtin_amdgcn_global_load_lds(                                                              \
        (const __attribute__((address_space(1))) unsigned int*)((SRC) + so0 + 64 * DIN),           \
        (__attribute__((address_space(3))) unsigned int*)(smem + (LDSB) + 4096 + tid * 8), 16, 0, 0);

#define GLALL(BUFW)                                                                                \
    { GL((BUFW) + 0,     aStage)             GL((BUFW) + 8192,  aStage + 128 * DIN)                \
      GL((BUFW) + 16384, bStage)             GL((BUFW) + 24576, bStage + 128 * DIN) }

#define LDA2(BUF, P)                                                                               \
    { UR for (int mt_ = 0; mt_ < 4; ++mt_) {                                                       \
        aF[mt_][0] = *(const s16x8*)&smem[(BUF) + aBase + mt_ * 2048 + sA[(P) * 2]];               \
        aF[mt_][1] = *(const s16x8*)&smem[(BUF) + aBase + mt_ * 2048 + sA[(P) * 2 + 1]]; } }

#define LDB2(BUF, P)                                                                               \
    { UR for (int nt_ = 0; nt_ < 2; ++nt_) {                                                       \
        bF[nt_][0] = *(const s16x8*)&smem[(BUF) + bBase + nt_ * 2048 + sA[(P) * 2]];               \
        bF[nt_][1] = *(const s16x8*)&smem[(BUF) + bBase + nt_ * 2048 + sA[(P) * 2 + 1]]; } }

#define MM32()                                                                                     \
    { __builtin_amdgcn_s_setprio(1);                                                               \
      UR for (int mt_ = 0; mt_ < 4; ++mt_)                                                         \
        UR for (int nt_ = 0; nt_ < 2; ++nt_)                                                       \
          UR for (int kk_ = 0; kk_ < 2; ++kk_)                                                     \
            acc[mt_][nt_] = __builtin_amdgcn_mfma_f32_32x32x16_bf16(                               \
                aF[mt_][kk_], bF[nt_][kk_], acc[mt_][nt_], 0, 0, 0);                               \
      __builtin_amdgcn_s_setprio(0); }

#define TILE(BUFR, BUFW, DOSTAGE)                                                                  \
    {                                                                                              \
        LDA2(BUFR, 0); LDB2(BUFR, 0);                                                              \
        if (DOSTAGE) { GLALL(BUFW); aStage += BK; bStage += BK; }                                  \
        MM32();                                                                                    \
        LDA2(BUFR, 1); LDB2(BUFR, 1);                                                              \
        MM32();                                                                                    \
        asm volatile("s_waitcnt vmcnt(0)" ::: "memory");                                           \
        asm volatile("s_barrier" ::: "memory");                                                    \
    }

    GLALL(0)
    aStage += BK; bStage += BK;
    asm volatile("s_waitcnt vmcnt(0)" ::: "memory");
    asm volatile("s_barrier" ::: "memory");

    for (int i = 0; i < 15; ++i) {
        TILE(0, 32768, 1);
        TILE(32768, 0, 1);
    }
    TILE(0, 32768, 1);
    TILE(32768, 0, 0);

#undef GL
#undef GLALL
#undef LDA2
#undef LDB2
#undef MM32
#undef TILE

    float bqv[2];
    UR for (int nt_ = 0; nt_ < 2; ++nt_)
        bqv[nt_] = bq[n0 + wn * 64 + nt_ * 32 + l31];

    for (int c = 0; c < 2; ++c) {
        if (((wv >> 1) & 1) == c) {
            UR for (int mt_ = 0; mt_ < 4; ++mt_)
                UR for (int nt_ = 0; nt_ < 2; ++nt_)
                    UR for (int r = 0; r < 16; ++r)
                        qsc[wm * 128 + mt_ * 32 + (r & 3) + 8 * (r >> 2) + 4 * lk]
                           [(wv & 1) * 64 + nt_ * 32 + l31] =
                            f2bf(acc[mt_][nt_][r] + bqv[nt_]);
        }
        __syncthreads();

        const float bvalc = 2.0f * bb[h * NG + ((nt * 2 + c) & 3)];
        {
            const int r2 = tid >> 1, ch = (tid & 1) * 64;
            const unsigned short* qrow = &qsc[r2][ch];
            const unsigned short* kg = kn_ws + (size_t)(m0 + r2) * (NH * DH) + h * DH + ch;
            const float* wp = &wsm[ch];
            float s2 = 0.f, skq = 0.f;
            UR for (int i = 0; i < 8; ++i) {
                u32x4 kv = *(const u32x4*)(kg + i * 8);
                UR for (int j = 0; j < 4; ++j) {
                    unsigned int qv = *(const unsigned int*)&qrow[i * 8 + j * 2];
                    unsigned int kw = kv[j];
                    float q0 = bf2f((unsigned short)(qv & 0xffff));
                    float q1 = bf2f((unsigned short)(qv >> 16));
                    float k0 = bf2f((unsigned short)(kw & 0xffff));
                    float k1 = bf2f((unsigned short)(kw >> 16));
                    s2  += q0 * q0 + q1 * q1;
                    skq += q0 * k0 * wp[i * 8 + j * 2] + q1 * k1 * wp[i * 8 + j * 2 + 1];
                }
            }
            s2  += __shfl_xor(s2, 1);
            skq += __shfl_xor(skq, 1);
            if ((tid & 1) == 0) {
                const float rs = rsqrtf(s2 * (1.0f / 128.0f) + 1e-6f) * 0.08838834764831845f;
                rms_l[r2] = rs;
                l_l[r2]   = skq * rs + bvalc;
            }
        }
        __syncthreads();

        {
            f32x4 sacc0 = f32x4{0.f, 0.f, 0.f, 0.f};
            f32x4 sacc1 = f32x4{0.f, 0.f, 0.f, 0.f};
            const int ar = wv * 32 + l15;
            const int kc = (lane >> 4) * 8;
            UR for (int ks = 0; ks < 4; ++ks) {
                s16x8 bf_ = *(const s16x8*)&kbn[l15][ks * 32 + kc];
                s16x8 a0  = *(const s16x8*)&qsc[ar][ks * 32 + kc];
                s16x8 a1  = *(const s16x8*)&qsc[ar + 16][ks * 32 + kc];
                sacc0 = __builtin_amdgcn_mfma_f32_16x16x32_bf16(a0, bf_, sacc0, 0, 0, 0);
                sacc1 = __builtin_amdgcn_mfma_f32_16x16x32_bf16(a1, bf_, sacc1, 0, 0, 0);
            }
            UR for (int mt = 0; mt < 2; ++mt) {
                f32x4 sa = mt ? sacc1 : sacc0;
                UR for (int r = 0; r < 4; ++r) {
                    const int row = wv * 32 + mt * 16 + (lane >> 4) * 4 + r;
                    float e = __expf(sa[r] * rms_l[row] - l_l[row]);
                    e += __shfl_xor(e, 1);
                    e += __shfl_xor(e, 2);
                    e += __shfl_xor(e, 4);
                    e += __shfl_xor(e, 8);
                    if (l15 == 0)
                        atomicAdd(&out[(size_t)h * S_TOK + m0 + row], 0.25f / (1.0f + e));
                }
            }
        }
        __syncthreads();
    }
}

extern "C" void kernel_launch(void* const* d_in, const int* in_sizes, int n_in,
                              void* d_out, int out_size, void* d_ws, size_t ws_size,
                              hipStream_t stream)
{
    const float* hid = (const float*)d_in[0];
    const float* Wq  = (const float*)d_in[1];
    const float* bq  = (const float*)d_in[2];
    const float* Wk  = (const float*)d_in[3];
    const float* qnw = (const float*)d_in[4];
    const float* knw = (const float*)d_in[5];
    const float* bb  = (const float*)d_in[6];
    const float* kb  = (const float*)d_in[7];
    float* out = (float*)d_out;

    (void)hipMemsetAsync(d_out, 0, (size_t)out_size * sizeof(float), stream);

    const size_t HID_E = (size_t)S_TOK * DIN;
    const size_t WQ_E  = (size_t)NH * NG * DH * DIN;
    const size_t WK_E  = (size_t)NH * DH * DIN;

    unsigned short* hid_b = (unsigned short*)d_ws;
    unsigned short* wq_b  = hid_b + HID_E;
    unsigned short* wk_b  = wq_b + WQ_E;
    unsigned short* kn_ws = wk_b + WK_E;

    cvt_all_kernel<<<2816, 256, 0, stream>>>(hid, Wq, Wk, hid_b, wq_b, wk_b);

    kproj256_bf16<<<dim3(4, S_TOK / 256), dim3(512), 0, stream>>>(hid_b, wk_b, knw, kn_ws);
    qscore_bf16<<<dim3(NH * NG / 2, S_TOK / 256), dim3(512), 0, stream>>>(hid_b, wq_b, bq, qnw, bb, kb, kn_ws, out);
}

// Round 17
// 746.667 us; speedup vs baseline: 1.0708x; 1.0708x over previous
//
#include <hip/hip_runtime.h>

#define S_TOK 32768
#define DIN   2048
#define NH    8
#define NG    4
#define DH    128
#define NSINK 16
#define BK    64

typedef float        f32x4 __attribute__((ext_vector_type(4)));
typedef short        s16x8 __attribute__((ext_vector_type(8)));
typedef unsigned int u32x4 __attribute__((ext_vector_type(4)));

#define UR _Pragma("unroll")

__device__ __forceinline__ unsigned short f2bf(float f) {
    unsigned int u = __builtin_bit_cast(unsigned int, f);
    u = (u + 0x7fffu + ((u >> 16) & 1u)) >> 16;
    return (unsigned short)u;
}
__device__ __forceinline__ float bf2f(unsigned short h) {
    unsigned int u = ((unsigned int)h) << 16;
    return __builtin_bit_cast(float, u);
}
__device__ __forceinline__ unsigned int pack2(float lo, float hi) {
    return (unsigned int)f2bf(lo) | ((unsigned int)f2bf(hi) << 16);
}

// ---------------- fused fp32 -> bf16 pre-conversion (3 segments, 1 launch)
__global__ __launch_bounds__(256) void cvt_all_kernel(const float* __restrict__ hid,
                                                      const float* __restrict__ wq,
                                                      const float* __restrict__ wk,
                                                      unsigned short* __restrict__ ohid,
                                                      unsigned short* __restrict__ owq,
                                                      unsigned short* __restrict__ owk)
{
    const float* in;
    unsigned short* out;
    int n8, i, stride;
    if (blockIdx.x < 2048) {
        in = hid; out = ohid; n8 = (S_TOK * DIN) / 8;
        i = blockIdx.x * 256 + threadIdx.x; stride = 2048 * 256;
    } else if (blockIdx.x < 2560) {
        in = wq; out = owq; n8 = (NH * NG * DH * DIN) / 8;
        i = (blockIdx.x - 2048) * 256 + threadIdx.x; stride = 512 * 256;
    } else {
        in = wk; out = owk; n8 = (NH * DH * DIN) / 8;
        i = (blockIdx.x - 2560) * 256 + threadIdx.x; stride = 256 * 256;
    }
    for (; i < n8; i += stride) {
        const float* p = in + (size_t)i * 8;
        float4 a = *(const float4*)p;
        float4 b = *(const float4*)(p + 4);
        u32x4 v;
        v.x = pack2(a.x, a.y); v.y = pack2(a.z, a.w);
        v.z = pack2(b.x, b.y); v.w = pack2(b.z, b.w);
        *(u32x4*)(out + (size_t)i * 8) = v;
    }
}

// ---------------- Kernel A (R13-proven): k-proj 256x256 tile
__global__ __launch_bounds__(512, 2) void kproj256_bf16(const unsigned short* __restrict__ hid,
                                                        const unsigned short* __restrict__ Wk,
                                                        const float* __restrict__ knw,
                                                        unsigned short* __restrict__ kn_ws)
{
    __shared__ alignas(16) unsigned short smem[65536];
    __shared__ float wsm[128];
    unsigned short (*qsc)[132] = (unsigned short(*)[132])smem;

    const int tid = threadIdx.x, lane = tid & 63, wv = tid >> 6;
    const int wm = wv >> 2, wn = wv & 3;
    const int nt = blockIdx.x;
    const int m0 = blockIdx.y * 256;
    const int n0 = nt * 256;

    if (tid < 128) wsm[tid] = knw[tid];

    const int srow = tid >> 3;
    const int so0 = srow * DIN + (((tid & 7) ^ (srow & 7)) * 8);

    const int l15 = lane & 15;
    const int slotA = ((lane >> 4) ^ (lane & 7)) * 8;
    const int aOff0 = (wm * 128 + l15) * 64 + slotA;
    const int aOff1 = aOff0 ^ 32;
    const int bOff0 = (wn * 64 + l15) * 64 + slotA;
    const int bOff1 = bOff0 ^ 32;

    const unsigned short* aStage = hid + (size_t)m0 * DIN;
    const unsigned short* bStage = Wk + (size_t)n0 * DIN;

    f32x4 acc[8][4];
    UR for (int m = 0; m < 8; ++m)
        UR for (int n = 0; n < 4; ++n)
            acc[m][n] = f32x4{0.f, 0.f, 0.f, 0.f};

    s16x8 aF[4][2], bF[4][2];

#define GL(LDSB, SRC)                                                                              \
    __builtin_amdgcn_global_load_lds(                                                              \
        (const __attribute__((address_space(1))) unsigned int*)((SRC) + so0),                      \
        (__attribute__((address_space(3))) unsigned int*)(smem + (LDSB) + tid * 8), 16, 0, 0);     \
    __builtin_amdgcn_global_load_lds(                                                              \
        (const __attribute__((address_space(1))) unsigned int*)((SRC) + so0 + 64 * DIN),           \
        (__attribute__((address_space(3))) unsigned int*)(smem + (LDSB) + 4096 + tid * 8), 16, 0, 0);

#define GLALL(BUFW)                                                                                \
    { GL((BUFW) + 0,     aStage)             GL((BUFW) + 8192,  aStage + 128 * DIN)                \
      GL((BUFW) + 16384, bStage)             GL((BUFW) + 24576, bStage + 128 * DIN) }

#define LDA(BUF, QH)                                                                               \
    { UR for (int i_ = 0; i_ < 4; ++i_) {                                                          \
        aF[i_][0] = *(const s16x8*)&smem[(BUF) + aOff0 + ((QH) * 4 + i_) * 1024];                  \
        aF[i_][1] = *(const s16x8*)&smem[(BUF) + aOff1 + ((QH) * 4 + i_) * 1024]; } }

#define LDB(BUF, NH2)                                                                              \
    { UR for (int j_ = 0; j_ < 2; ++j_) {                                                          \
        bF[(NH2) * 2 + j_][0] = *(const s16x8*)&smem[(BUF) + 16384 + bOff0 + ((NH2) * 2 + j_) * 1024]; \
        bF[(NH2) * 2 + j_][1] = *(const s16x8*)&smem[(BUF) + 16384 + bOff1 + ((NH2) * 2 + j_) * 1024]; } }

#define MFMAQ(MF0, NF0)                                                                            \
    { __builtin_amdgcn_s_setprio(1);                                                               \
      UR for (int i_ = 0; i_ < 4; ++i_)                                                            \
        UR for (int j_ = 0; j_ < 2; ++j_)                                                          \
          UR for (int k_ = 0; k_ < 2; ++k_)                                                        \
            acc[(MF0) + i_][(NF0) + j_] = __builtin_amdgcn_mfma_f32_16x16x32_bf16(                 \
                aF[i_][k_], bF[(NF0) + j_][k_], acc[(MF0) + i_][(NF0) + j_], 0, 0, 0);             \
      __builtin_amdgcn_s_setprio(0); }

#define TILE(BUFR, BUFW, DOSTAGE)                                                                  \
    {                                                                                              \
        LDA(BUFR, 0); LDB(BUFR, 0);                                                                \
        if (DOSTAGE) { GLALL(BUFW); aStage += BK; bStage += BK; }                                  \
        MFMAQ(0, 0);                                                                               \
        LDB(BUFR, 1);                                                                              \
        MFMAQ(0, 2);                                                                               \
        LDA(BUFR, 1);                                                                              \
        MFMAQ(4, 2);                                                                               \
        MFMAQ(4, 0);                                                                               \
        asm volatile("s_waitcnt vmcnt(0)" ::: "memory");                                           \
        asm volatile("s_barrier" ::: "memory");                                                    \
    }

    GLALL(0)
    aStage += BK; bStage += BK;
    asm volatile("s_waitcnt vmcnt(0)" ::: "memory");
    asm volatile("s_barrier" ::: "memory");

    for (int i = 0; i < 15; ++i) {
        TILE(0, 32768, 1);
        TILE(32768, 0, 1);
    }
    TILE(0, 32768, 1);
    TILE(32768, 0, 0);

#undef GL
#undef GLALL
#undef LDA
#undef LDB
#undef MFMAQ
#undef TILE

    for (int c = 0; c < 2; ++c) {
        if (((wv >> 1) & 1) == c) {
            UR for (int mf = 0; mf < 8; ++mf)
                UR for (int nf = 0; nf < 4; ++nf)
                    UR for (int r = 0; r < 4; ++r)
                        qsc[wm * 128 + mf * 16 + (lane >> 4) * 4 + r][(wv & 1) * 64 + nf * 16 + l15] =
                            f2bf(acc[mf][nf][r]);
        }
        __syncthreads();

        {
            const int r2 = tid >> 1, ch = (tid & 1) * 64;
            const unsigned short* row = &qsc[r2][ch];
            float s2 = 0.f;
            UR for (int dw = 0; dw < 32; ++dw) {
                unsigned int v = *(const unsigned int*)&row[dw * 2];
                float f0 = bf2f((unsigned short)(v & 0xffff));
                float f1 = bf2f((unsigned short)(v >> 16));
                s2 += f0 * f0 + f1 * f1;
            }
            s2 += __shfl_xor(s2, 1);
            const float rq = rsqrtf(s2 * (1.0f / 128.0f) + 1e-6f);

            const int hc = nt * 2 + c;
            unsigned short* dst = kn_ws + (size_t)(m0 + r2) * (NH * DH) + hc * DH + ch;
            UR for (int i = 0; i < 8; ++i) {
                u32x4 v;
                float f0, f1;
                f0 = bf2f(row[i * 8 + 0]) * rq * wsm[ch + i * 8 + 0];
                f1 = bf2f(row[i * 8 + 1]) * rq * wsm[ch + i * 8 + 1];
                v.x = pack2(f0, f1);
                f0 = bf2f(row[i * 8 + 2]) * rq * wsm[ch + i * 8 + 2];
                f1 = bf2f(row[i * 8 + 3]) * rq * wsm[ch + i * 8 + 3];
                v.y = pack2(f0, f1);
                f0 = bf2f(row[i * 8 + 4]) * rq * wsm[ch + i * 8 + 4];
                f1 = bf2f(row[i * 8 + 5]) * rq * wsm[ch + i * 8 + 5];
                v.z = pack2(f0, f1);
                f0 = bf2f(row[i * 8 + 6]) * rq * wsm[ch + i * 8 + 6];
                f1 = bf2f(row[i * 8 + 7]) * rq * wsm[ch + i * 8 + 7];
                v.w = pack2(f0, f1);
                *(u32x4*)(dst + i * 8) = v;
            }
        }
        __syncthreads();
    }
}

// ---------------- Kernel B (R8-proven, frozen): 256x256-tile q-proj + RMSNorm + MFMA sink gate
__global__ __launch_bounds__(512, 2) void qscore_bf16(const unsigned short* __restrict__ hid,
                                                      const unsigned short* __restrict__ Wq,
                                                      const float* __restrict__ bq,
                                                      const float* __restrict__ qnw,
                                                      const float* __restrict__ bb,
                                                      const float* __restrict__ kbase,
                                                      const unsigned short* __restrict__ kn_ws,
                                                      float* __restrict__ out)
{
    __shared__ alignas(16) unsigned short smem[65536];
    __shared__ alignas(16) unsigned short kbn[NSINK][136];
    __shared__ float rms_l[256];
    __shared__ float l_l[256];
    __shared__ float wsm[128];
    unsigned short (*qsc)[132] = (unsigned short(*)[132])smem;

    const int tid = threadIdx.x, lane = tid & 63, wv = tid >> 6;
    const int wm = wv >> 2, wn = wv & 3;
    const int nt = blockIdx.x;
    const int m0 = blockIdx.y * 256;
    const int n0 = nt * 256;
    const int h  = nt >> 1;

    if (tid < 128) wsm[tid] = qnw[tid];
    if (tid < 256) {
        const int ts = tid >> 4, d0 = (tid & 15) * 8;
        const float* src = kbase + ((size_t)h * NSINK + ts) * DH + d0;
        float4 x = *(const float4*)src;
        float4 y = *(const float4*)(src + 4);
        const float* w = qnw + d0;
        u32x4 v;
        v.x = pack2(x.x * w[0], x.y * w[1]);
        v.y = pack2(x.z * w[2], x.w * w[3]);
        v.z = pack2(y.x * w[4], y.y * w[5]);
        v.w = pack2(y.z * w[6], y.w * w[7]);
        *(u32x4*)&kbn[ts][d0] = v;
    }

    const int srow = tid >> 3;
    const int so0 = srow * DIN + (((tid & 7) ^ (srow & 7)) * 8);

    const int l15 = lane & 15;
    const int slotA = ((lane >> 4) ^ (lane & 7)) * 8;
    const int aOff0 = (wm * 128 + l15) * 64 + slotA;
    const int aOff1 = aOff0 ^ 32;
    const int bOff0 = (wn * 64 + l15) * 64 + slotA;
    const int bOff1 = bOff0 ^ 32;

    const unsigned short* aStage = hid + (size_t)m0 * DIN;
    const unsigned short* bStage = Wq + (size_t)n0 * DIN;

    f32x4 acc[8][4];
    UR for (int m = 0; m < 8; ++m)
        UR for (int n = 0; n < 4; ++n)
            acc[m][n] = f32x4{0.f, 0.f, 0.f, 0.f};

    s16x8 aF[4][2], bF[4][2];

#define GL(LDSB, SRC)                                                                              \
    __builtin_amdgcn_global_load_lds(                                                              \
        (const __attribute__((address_space(1))) unsigned int*)((SRC) + so0),                      \
        (__attribute__((address_space(3))) unsigned int*)(smem + (LDSB) + tid * 8), 16, 0, 0);     \
    __builtin_amdgcn_global_load_lds(                                                              \
        (const __attribute__((address_space(1))) unsigned int*)((SRC) + so0 + 64 * DIN),           \
        (__attribute__((address_space(3))) unsigned int*)(smem + (LDSB) + 4096 + tid * 8), 16, 0, 0);

#define GLALL(BUFW)                                                                                \
    { GL((BUFW) + 0,     aStage)             GL((BUFW) + 8192,  aStage + 128 * DIN)                \
      GL((BUFW) + 16384, bStage)             GL((BUFW) + 24576, bStage + 128 * DIN) }

#define LDA(BUF, QH)                                                                               \
    { UR for (int i_ = 0; i_ < 4; ++i_) {                                                          \
        aF[i_][0] = *(const s16x8*)&smem[(BUF) + aOff0 + ((QH) * 4 + i_) * 1024];                  \
        aF[i_][1] = *(const s16x8*)&smem[(BUF) + aOff1 + ((QH) * 4 + i_) * 1024]; } }

#define LDB(BUF, NH2)                                                                              \
    { UR for (int j_ = 0; j_ < 2; ++j_) {                                                          \
        bF[(NH2) * 2 + j_][0] = *(const s16x8*)&smem[(BUF) + 16384 + bOff0 + ((NH2) * 2 + j_) * 1024]; \
        bF[(NH2) * 2 + j_][1] = *(const s16x8*)&smem[(BUF) + 16384 + bOff1 + ((NH2) * 2 + j_) * 1024]; } }

#define MFMAQ(MF0, NF0)                                                                            \
    { __builtin_amdgcn_s_setprio(1);                                                               \
      UR for (int i_ = 0; i_ < 4; ++i_)                                                            \
        UR for (int j_ = 0; j_ < 2; ++j_)                                                          \
          UR for (int k_ = 0; k_ < 2; ++k_)                                                        \
            acc[(MF0) + i_][(NF0) + j_] = __builtin_amdgcn_mfma_f32_16x16x32_bf16(                 \
                aF[i_][k_], bF[(NF0) + j_][k_], acc[(MF0) + i_][(NF0) + j_], 0, 0, 0);             \
      __builtin_amdgcn_s_setprio(0); }

#define TILE(BUFR, BUFW, DOSTAGE)                                                                  \
    {                                                                                              \
        LDA(BUFR, 0); LDB(BUFR, 0);                                                                \
        if (DOSTAGE) { GLALL(BUFW); aStage += BK; bStage += BK; }                                  \
        MFMAQ(0, 0);                                                                               \
        LDB(BUFR, 1);                                                                              \
        MFMAQ(0, 2);                                                                               \
        LDA(BUFR, 1);                                                                              \
        MFMAQ(4, 2);                                                                               \
        MFMAQ(4, 0);                                                                               \
        asm volatile("s_waitcnt vmcnt(0)" ::: "memory");                                           \
        asm volatile("s_barrier" ::: "memory");                                                    \
    }

    GLALL(0)
    aStage += BK; bStage += BK;
    asm volatile("s_waitcnt vmcnt(0)" ::: "memory");
    asm volatile("s_barrier" ::: "memory");

    for (int i = 0; i < 15; ++i) {
        TILE(0, 32768, 1);
        TILE(32768, 0, 1);
    }
    TILE(0, 32768, 1);
    TILE(32768, 0, 0);

#undef GL
#undef GLALL
#undef LDA
#undef LDB
#undef MFMAQ
#undef TILE

    float bqv[4];
    UR for (int nf = 0; nf < 4; ++nf)
        bqv[nf] = bq[n0 + wn * 64 + nf * 16 + l15];

    for (int c = 0; c < 2; ++c) {
        if (((wv >> 1) & 1) == c) {
            UR for (int mf = 0; mf < 8; ++mf)
                UR for (int nf = 0; nf < 4; ++nf)
                    UR for (int r = 0; r < 4; ++r)
                        qsc[wm * 128 + mf * 16 + (lane >> 4) * 4 + r][(wv & 1) * 64 + nf * 16 + l15] =
                            f2bf(acc[mf][nf][r] + bqv[nf]);
        }
        __syncthreads();

        const float bvalc = 2.0f * bb[h * NG + ((nt * 2 + c) & 3)];
        {
            const int r2 = tid >> 1, ch = (tid & 1) * 64;
            const unsigned short* qrow = &qsc[r2][ch];
            const unsigned short* kg = kn_ws + (size_t)(m0 + r2) * (NH * DH) + h * DH + ch;
            const float* wp = &wsm[ch];
            float s2 = 0.f, skq = 0.f;
            UR for (int i = 0; i < 8; ++i) {
                u32x4 kv = *(const u32x4*)(kg + i * 8);
                UR for (int j = 0; j < 4; ++j) {
                    unsigned int qv = *(const unsigned int*)&qrow[i * 8 + j * 2];
                    unsigned int kw = kv[j];
                    float q0 = bf2f((unsigned short)(qv & 0xffff));
                    float q1 = bf2f((unsigned short)(qv >> 16));
                    float k0 = bf2f((unsigned short)(kw & 0xffff));
                    float k1 = bf2f((unsigned short)(kw >> 16));
                    s2  += q0 * q0 + q1 * q1;
                    skq += q0 * k0 * wp[i * 8 + j * 2] + q1 * k1 * wp[i * 8 + j * 2 + 1];
                }
            }
            s2  += __shfl_xor(s2, 1);
            skq += __shfl_xor(skq, 1);
            if ((tid & 1) == 0) {
                const float rs = rsqrtf(s2 * (1.0f / 128.0f) + 1e-6f) * 0.08838834764831845f;
                rms_l[r2] = rs;
                l_l[r2]   = skq * rs + bvalc;
            }
        }
        __syncthreads();

        {
            f32x4 sacc0 = f32x4{0.f, 0.f, 0.f, 0.f};
            f32x4 sacc1 = f32x4{0.f, 0.f, 0.f, 0.f};
            const int ar = wv * 32 + l15;
            const int kc = (lane >> 4) * 8;
            UR for (int ks = 0; ks < 4; ++ks) {
                s16x8 bf_ = *(const s16x8*)&kbn[l15][ks * 32 + kc];
                s16x8 a0  = *(const s16x8*)&qsc[ar][ks * 32 + kc];
                s16x8 a1  = *(const s16x8*)&qsc[ar + 16][ks * 32 + kc];
                sacc0 = __builtin_amdgcn_mfma_f32_16x16x32_bf16(a0, bf_, sacc0, 0, 0, 0);
                sacc1 = __builtin_amdgcn_mfma_f32_16x16x32_bf16(a1, bf_, sacc1, 0, 0, 0);
            }
            UR for (int mt = 0; mt < 2; ++mt) {
                f32x4 sa = mt ? sacc1 : sacc0;
                UR for (int r = 0; r < 4; ++r) {
                    const int row = wv * 32 + mt * 16 + (lane >> 4) * 4 + r;
                    float e = __expf(sa[r] * rms_l[row] - l_l[row]);
                    e += __shfl_xor(e, 1);
                    e += __shfl_xor(e, 2);
                    e += __shfl_xor(e, 4);
                    e += __shfl_xor(e, 8);
                    if (l15 == 0)
                        atomicAdd(&out[(size_t)h * S_TOK + m0 + row], 0.25f / (1.0f + e));
                }
            }
        }
        __syncthreads();
    }
}

extern "C" void kernel_launch(void* const* d_in, const int* in_sizes, int n_in,
                              void* d_out, int out_size, void* d_ws, size_t ws_size,
                              hipStream_t stream)
{
    const float* hid = (const float*)d_in[0];
    const float* Wq  = (const float*)d_in[1];
    const float* bq  = (const float*)d_in[2];
    const float* Wk  = (const float*)d_in[3];
    const float* qnw = (const float*)d_in[4];
    const float* knw = (const float*)d_in[5];
    const float* bb  = (const float*)d_in[6];
    const float* kb  = (const float*)d_in[7];
    float* out = (float*)d_out;

    (void)hipMemsetAsync(d_out, 0, (size_t)out_size * sizeof(float), stream);

    const size_t HID_E = (size_t)S_TOK * DIN;
    const size_t WQ_E  = (size_t)NH * NG * DH * DIN;
    const size_t WK_E  = (size_t)NH * DH * DIN;

    unsigned short* hid_b = (unsigned short*)d_ws;
    unsigned short* wq_b  = hid_b + HID_E;
    unsigned short* wk_b  = wq_b + WQ_E;
    unsigned short* kn_ws = wk_b + WK_E;

    cvt_all_kernel<<<2816, 256, 0, stream>>>(hid, Wq, Wk, hid_b, wq_b, wk_b);

    kproj256_bf16<<<dim3(4, S_TOK / 256), dim3(512), 0, stream>>>(hid_b, wk_b, knw, kn_ws);
    qscore_bf16<<<dim3(NH * NG / 2, S_TOK / 256), dim3(512), 0, stream>>>(hid_b, wq_b, bq, qnw, bb, kb, kn_ws, out);
}